// Round 9
// baseline (186.065 us; speedup 1.0000x reference)
//
#include <hip/hip_runtime.h>
#include <stdint.h>

#define N_NODES 2048
#define N_BATCH 4

__device__ __forceinline__ uint32_t bf16rn(float x) {
    uint32_t u = __float_as_uint(x);
    u += 0x7fffu + ((u >> 16) & 1u);
    return u >> 16;
}

// ---- Kernel 1: build the packed sin/cos(theta) table in GLOBAL memory ----
// entry (b*N+j): dword d = (bf16(cos th_jd)<<16) | bf16(sin th_jd).
// 8192 entries x 16 B = 128 KB in d_ws; L2/L3-resident for the main kernel.
__global__ __launch_bounds__(256) void table_kernel(
    const float* __restrict__ theta, uint4* __restrict__ tbl)
{
    const int idx = blockIdx.x * 256 + threadIdx.x;      // (b*N + j)
    const float4 u = *(const float4*)(theta + (size_t)idx * 4);
    const float th[4] = {u.x, u.y, u.z, u.w};
    uint32_t p[4];
    #pragma unroll
    for (int d = 0; d < 4; ++d) {
        float s, c;
        __sincosf(th[d], &s, &c);
        p[d] = (bf16rn(c) << 16) | bf16rn(s);
    }
    tbl[idx] = make_uint4(p[0], p[1], p[2], p[3]);
}

// ---- Kernel 2: copy-shaped main kernel ----
// R0/R2/R4/R5/R8 all pinned at ~11.4 GB/s/CU. The m13 copy does 24.6 GB/s/CU
// with 32 waves/CU AND ~128 KB/CU in flight -- a combination the 32 KB
// per-block LDS table made impossible. Table now global -> ~0 LDS -> one
// 256-thread block per row, 8 blocks/CU resident: each thread issues its
// full 64 B of W+alpha as straight-line loads (16 KB/block in flight),
// giving 32 waves/CU TLP and ~128 KB/CU of HBM-latency bytes outstanding.
__global__ __launch_bounds__(256, 8) void kuramoto_kernel(
    const float* __restrict__ gamma,
    const float* __restrict__ W,
    const float* __restrict__ alpha,
    const uint4* __restrict__ tbl,
    float* __restrict__ out)
{
    __shared__ float red[4][8];   // per-wave partials (128 B)

    const int tid  = threadIdx.x;
    const int lane = tid & 63;
    const int wave = tid >> 6;
    const int b = blockIdx.x >> 11;            // 2048 blocks per batch
    const int i = blockIdx.x & (N_NODES - 1);  // one row per block

    const size_t rowbase = ((size_t)b * N_NODES + i) * N_NODES;
    const int j0 = tid * 8;                    // 8 consecutive j per thread

    // Whole row in flight: 4 long-latency dwordx4 per thread, no loop.
    const float4 w0 = *(const float4*)(W     + rowbase + j0);
    const float4 w1 = *(const float4*)(W     + rowbase + j0 + 4);
    const float4 a0 = *(const float4*)(alpha + rowbase + j0);
    const float4 a1 = *(const float4*)(alpha + rowbase + j0 + 4);

    // table slice for this thread's 8 j: 128 B contiguous, L2-hit
    const uint4* tb = tbl + ((size_t)b * N_NODES + j0);

    //   im_d = sum_j (A*s_jd - B*c_jd),  re_d = sum_j (A*c_jd + B*s_jd)
    //   A = W*cos(alpha), B = W*sin(alpha)
    float re[4] = {0.f, 0.f, 0.f, 0.f};
    float im[4] = {0.f, 0.f, 0.f, 0.f};

    #pragma unroll
    for (int h = 0; h < 2; ++h) {
        const float4 wv = h ? w1 : w0;
        const float4 av = h ? a1 : a0;
        const uint4 t0 = tb[h * 4 + 0];
        const uint4 t1 = tb[h * 4 + 1];
        const uint4 t2 = tb[h * 4 + 2];
        const uint4 t3 = tb[h * 4 + 3];
        const float wq[4] = {wv.x, wv.y, wv.z, wv.w};
        const float aq[4] = {av.x, av.y, av.z, av.w};
        #pragma unroll
        for (int q = 0; q < 4; ++q) {
            float sa, ca;
            __sincosf(aq[q], &sa, &ca);
            const float A  = wq[q] * ca;
            const float Bq = wq[q] * sa;
            const uint4 t = (q == 0) ? t0 : (q == 1) ? t1 : (q == 2) ? t2 : t3;
            const uint32_t tu[4] = {t.x, t.y, t.z, t.w};
            #pragma unroll
            for (int d = 0; d < 4; ++d) {
                const float s = __uint_as_float(tu[d] << 16);
                const float c = __uint_as_float(tu[d] & 0xffff0000u);
                re[d] = fmaf(A,   c, re[d]);
                re[d] = fmaf(Bq,  s, re[d]);
                im[d] = fmaf(A,   s, im[d]);
                im[d] = fmaf(-Bq, c, im[d]);
            }
        }
    }

    // ---- Reduction: 6-stage butterfly within wave, then 4 waves via LDS ----
    #pragma unroll
    for (int stage = 1; stage < 64; stage <<= 1) {
        #pragma unroll
        for (int d = 0; d < 4; ++d) {
            re[d] += __shfl_xor(re[d], stage, 64);
            im[d] += __shfl_xor(im[d], stage, 64);
        }
    }
    if (lane == 0) {
        #pragma unroll
        for (int d = 0; d < 4; ++d) {
            red[wave][d]     = re[d];
            red[wave][4 + d] = im[d];
        }
    }
    __syncthreads();

    if (tid == 0) {
        float R[4], I[4];
        #pragma unroll
        for (int d = 0; d < 4; ++d) {
            R[d] = red[0][d]     + red[1][d]     + red[2][d]     + red[3][d];
            I[d] = red[0][4 + d] + red[1][4 + d] + red[2][4 + d] + red[3][4 + d];
        }
        const size_t obase = ((size_t)b * N_NODES + i) * 4;
        const uint4 ti = tbl[(size_t)b * N_NODES + i];   // s_i, c_i from table
        const uint32_t tiu[4] = {ti.x, ti.y, ti.z, ti.w};
        const float4 g4 = *(const float4*)(gamma + obase);
        const float gd[4] = {g4.x, g4.y, g4.z, g4.w};
        float t[4];
        float s2 = 0.0f;
        #pragma unroll
        for (int d = 0; d < 4; ++d) {
            const float s_i = __uint_as_float(tiu[d] << 16);
            const float c_i = __uint_as_float(tiu[d] & 0xffff0000u);
            const float coup = (c_i * I[d] - s_i * R[d]) * (1.0f / (float)N_NODES);
            t[d] = gd[d] + coup;   // theta + (gamma-theta) + coupling (DT=ATTR=1)
            s2 = fmaf(t[d], t[d], s2);
        }
        const float inv = 1.0f / fmaxf(sqrtf(s2), 1e-6f);
        *(float4*)(out + obase) = make_float4(t[0]*inv, t[1]*inv, t[2]*inv, t[3]*inv);
    }
}

extern "C" void kernel_launch(void* const* d_in, const int* in_sizes, int n_in,
                              void* d_out, int out_size, void* d_ws, size_t ws_size,
                              hipStream_t stream) {
    const float* theta = (const float*)d_in[0];
    const float* gamma = (const float*)d_in[1];
    const float* W     = (const float*)d_in[2];
    const float* alpha = (const float*)d_in[3];
    float* out = (float*)d_out;
    uint4* tbl = (uint4*)d_ws;   // needs 8192 * 16 B = 128 KB of workspace

    // kernel 1: 8192 table entries, 32 blocks x 256 threads
    hipLaunchKernelGGL(table_kernel, dim3((N_BATCH * N_NODES) / 256), dim3(256),
                       0, stream, theta, tbl);
    // kernel 2: one block per row
    hipLaunchKernelGGL(kuramoto_kernel, dim3(N_BATCH * N_NODES), dim3(256),
                       0, stream, gamma, W, alpha, tbl, out);
}

// Round 10
// 151.467 us; speedup vs baseline: 1.2284x; 1.2284x over previous
//
#include <hip/hip_runtime.h>
#include <stdint.h>

#define N_NODES 2048
#define N_BATCH 4
#define ROWS_PER_BLOCK 8
#define THREADS 512   // 8 waves, one row per wave

__device__ __forceinline__ uint32_t bf16rn(float x) {
    uint32_t u = __float_as_uint(x);
    u += 0x7fffu + ((u >> 16) & 1u);
    return u >> 16;
}

// SESSION-BEST kernel (R2), restored after R9 regressed.
//
// Roofline evidence (R0/R2/R4/R5/R8/R9): six structurally distinct variants
// (32-wave TLP, register MLP, LDS-DMA counted-vmcnt pipeline, L2-warming
// prefetch, copy-shaped block-per-row) all deliver 2.85-2.90 TB/s of reads
// = ~92% of the m13 copy benchmark's per-direction rate (6.29 TB/s counts
// R+W). 134 MB compulsory reads / ~2.9-3.15 TB/s read delivery = 43-46 us;
// this kernel measures 46.1-46.5 us with VALUBusy 27%, zero conflicts,
// zero spill, FETCH at the compulsory minimum. The binding resource is the
// chip's read-delivery path, not kernel structure.
__global__ __launch_bounds__(THREADS, 8) void kuramoto_kernel(
    const float* __restrict__ theta,
    const float* __restrict__ gamma,
    const float* __restrict__ W,
    const float* __restrict__ alpha,
    float* __restrict__ out)
{
    // SoA by d: tbl[d][j] = (bf16(cos th_jd)<<16) | bf16(sin th_jd)
    // Lane owns 4 consecutive j -> per-d read is ds_read_b128 at lane
    // stride 16B = the conflict-free pattern.
    __shared__ uint32_t tbl[4][N_NODES];

    const int tid  = threadIdx.x;
    const int lane = tid & 63;
    const int wave = tid >> 6;
    const int b    = blockIdx.x >> 8;                      // 256 blocks per batch
    const int i    = ((blockIdx.x & 255) * ROWS_PER_BLOCK) + wave;

    const size_t rowbase = ((size_t)b * N_NODES + i) * N_NODES;
    const float* Wr = W + rowbase;
    const float* Ar = alpha + rowbase;

    // ---- Issue first W/alpha tile BEFORE phase 1: its latency hides under
    // the table build + barrier instead of stalling the loop head.
    const int jfirst = lane * 4;
    float4 wc = *(const float4*)(Wr + jfirst);   // global_load_dwordx4
    float4 ac = *(const float4*)(Ar + jfirst);

    // ---- Phase 1: stage sin/cos(theta[b,:,:]) into LDS, bf16-packed ----
    const float* thb = theta + (size_t)b * (N_NODES * 4);
    #pragma unroll
    for (int g = 0; g < N_NODES / THREADS; ++g) {
        const int j = tid + g * THREADS;
        const float4 u = *(const float4*)(thb + (size_t)j * 4);  // coalesced
        const float th[4] = {u.x, u.y, u.z, u.w};
        #pragma unroll
        for (int d = 0; d < 4; ++d) {
            float s, c;
            __sincosf(th[d], &s, &c);
            tbl[d][j] = (bf16rn(c) << 16) | bf16rn(s);  // stride 4B: conflict-free
        }
    }
    __syncthreads();

    // ---- Phase 2: rolled 1-deep pipeline; lane handles j0..j0+3 per iter ----
    //   im_d = sum_j (A*s_jd - B*c_jd),  re_d = sum_j (A*c_jd + B*s_jd)
    //   A = W*cos(alpha), B = W*sin(alpha)
    float re[4] = {0.f, 0.f, 0.f, 0.f};
    float im[4] = {0.f, 0.f, 0.f, 0.f};

    #define CONSUME(WV, AV, J0)                                              \
    do {                                                                     \
        const float wq_[4] = {(WV).x, (WV).y, (WV).z, (WV).w};               \
        const float aq_[4] = {(AV).x, (AV).y, (AV).z, (AV).w};               \
        float A_[4], Bq_[4];                                                 \
        _Pragma("unroll")                                                    \
        for (int q = 0; q < 4; ++q) {                                        \
            float sa_, ca_;                                                  \
            __sincosf(aq_[q], &sa_, &ca_);                                   \
            A_[q]  = wq_[q] * ca_;                                           \
            Bq_[q] = wq_[q] * sa_;                                           \
        }                                                                    \
        _Pragma("unroll")                                                    \
        for (int d = 0; d < 4; ++d) {                                        \
            const uint4 t_ = *(const uint4*)&tbl[d][(J0)];  /* one tile live */ \
            const uint32_t tu_[4] = {t_.x, t_.y, t_.z, t_.w};                \
            _Pragma("unroll")                                                \
            for (int q = 0; q < 4; ++q) {                                    \
                const float s_ = __uint_as_float(tu_[q] << 16);              \
                const float c_ = __uint_as_float(tu_[q] & 0xffff0000u);      \
                re[d] = fmaf(A_[q],   c_, re[d]);                            \
                re[d] = fmaf(Bq_[q],  s_, re[d]);                            \
                im[d] = fmaf(A_[q],   s_, im[d]);                            \
                im[d] = fmaf(-Bq_[q], c_, im[d]);                            \
            }                                                                \
        }                                                                    \
    } while (0)

    // steady state: issue next tile, consume current, rotate. Rolled so the
    // scheduler can't hoist all prefetches and re-create R1's spill.
    #pragma unroll 1
    for (int it = 0; it < N_NODES / 256 - 1; ++it) {
        const int j0 = it * 256 + lane * 4;
        const float4 wn = *(const float4*)(Wr + j0 + 256);
        const float4 an = *(const float4*)(Ar + j0 + 256);
        CONSUME(wc, ac, j0);
        wc = wn; ac = an;
    }
    CONSUME(wc, ac, (N_NODES / 256 - 1) * 256 + lane * 4);  // epilogue
    #undef CONSUME

    // ---- Reduction: 6-stage butterfly over 64 lanes, 8 accumulators ----
    #pragma unroll
    for (int stage = 1; stage < 64; stage <<= 1) {
        #pragma unroll
        for (int d = 0; d < 4; ++d) {
            re[d] += __shfl_xor(re[d], stage, 64);
            im[d] += __shfl_xor(im[d], stage, 64);
        }
    }

    if (lane == 0) {
        const size_t obase = ((size_t)b * N_NODES + i) * 4;
        const float4 th4 = *(const float4*)(thb + (size_t)i * 4);
        const float4 g4  = *(const float4*)(gamma + obase);
        const float thd[4] = {th4.x, th4.y, th4.z, th4.w};
        const float gd[4]  = {g4.x, g4.y, g4.z, g4.w};
        float t[4];
        float s2 = 0.0f;
        #pragma unroll
        for (int d = 0; d < 4; ++d) {
            float s_i, c_i;
            __sincosf(thd[d], &s_i, &c_i);
            const float coup = (c_i * im[d] - s_i * re[d]) * (1.0f / (float)N_NODES);
            t[d] = gd[d] + coup;   // theta + (gamma-theta) + coupling  (DT=ATTR=1)
            s2 = fmaf(t[d], t[d], s2);
        }
        const float inv = 1.0f / fmaxf(sqrtf(s2), 1e-6f);
        *(float4*)(out + obase) = make_float4(t[0]*inv, t[1]*inv, t[2]*inv, t[3]*inv);
    }
}

extern "C" void kernel_launch(void* const* d_in, const int* in_sizes, int n_in,
                              void* d_out, int out_size, void* d_ws, size_t ws_size,
                              hipStream_t stream) {
    const float* theta = (const float*)d_in[0];
    const float* gamma = (const float*)d_in[1];
    const float* W     = (const float*)d_in[2];
    const float* alpha = (const float*)d_in[3];
    float* out = (float*)d_out;

    const int grid = (N_BATCH * N_NODES) / ROWS_PER_BLOCK;  // 1024 blocks = 4/CU
    hipLaunchKernelGGL(kuramoto_kernel, dim3(grid), dim3(THREADS), 0, stream,
                       theta, gamma, W, alpha, out);
}